// Round 3
// baseline (167.444 us; speedup 1.0000x reference)
//
#include <hip/hip_runtime.h>

typedef __attribute__((ext_vector_type(4))) float f32x4;
typedef __attribute__((ext_vector_type(8))) short s16x8;
typedef __attribute__((ext_vector_type(4))) unsigned int u32x4;

// float -> bf16 bits, round-nearest-even
__device__ __forceinline__ unsigned int f2bf(float f) {
  unsigned int u = __float_as_uint(f);
  u += 0x7fffu + ((u >> 16) & 1u);
  return u >> 16;
}

// ---------------------------------------------------------------------------
// Kernel 0 (unchanged from R2, verified passing): repack weight fp32->bf16
// MFMA A-fragments for v_mfma_f32_16x16x32_bf16:
//   wf[((ch*8 + mt)*64 + lane)*8 + j] = bf16(W[mt*16+(lane&15)]
//                                            [cc*32 + (lane>>4)*8 + j][tap])
// ch = cc*9 + tap. 294912 B of d_ws.
// ---------------------------------------------------------------------------
__global__ __launch_bounds__(256) void wtrans_kernel(const float* __restrict__ w,
                                                     unsigned short* __restrict__ wf) {
  int tid = blockIdx.x * 256 + threadIdx.x;   // 0..18431
  int l  = tid & 63;
  int mt = (tid >> 6) & 7;
  int ch = tid >> 9;                          // 0..35
  int cc = ch / 9, tap = ch - cc * 9;
  int co = mt * 16 + (l & 15);
  int cb = cc * 32 + (l >> 4) * 8;
  unsigned int r[8];
#pragma unroll
  for (int j = 0; j < 8; ++j)
    r[j] = f2bf(w[(co * 128 + cb + j) * 9 + tap]);
  u32x4 pk;
  pk.x = r[0] | (r[1] << 16);
  pk.y = r[2] | (r[3] << 16);
  pk.z = r[4] | (r[5] << 16);
  pk.w = r[6] | (r[7] << 16);
  *reinterpret_cast<u32x4*>(wf + (size_t)tid * 8) = pk;
}

// ---------------------------------------------------------------------------
// Main kernel, round 3: BARRIER-FREE K-loop (wave-private gather -> MFMA).
// Block = (b, ho), 512 blocks x 256 thr. Wave w owns wo in [16w,16w+16) and
// ALL 128 Cout (8 m-tiles). Lane l gathers channels (l>>4)*8+j at position
// 16w+(l&15): that IS the 16x16x32 B-fragment -> no LDS cols tile, no
// __syncthreads in the loop, compiler free to pipeline gathers over MFMAs.
// A-fragments are coalesced 16B/lane reads from repacked wf (L1-shared by the
// block's 4 waves). Separable bilinear: 2 dwordx2 row-pair loads per channel,
// validity folded into 4 weights. b = bid&7 keeps x XCD-affine.
// ---------------------------------------------------------------------------
__global__ __launch_bounds__(256, 2) void deform_kernel(const float* __restrict__ x,
                                                        const float* __restrict__ off,
                                                        const unsigned short* __restrict__ wf,
                                                        float* __restrict__ out) {
  __shared__ int2   sPos[576];   // [tap*64+wo] row0/row1 base addrs (clamped)
  __shared__ float4 sWt[576];    // [tap*64+wo] folded bilinear weights

  const int tid = threadIdx.x;
  const int bid = blockIdx.x;
  const int b  = bid & 7;        // XCD-affine batch
  const int ho = bid >> 3;

  // --- precompute sampling addresses + separable folded weights (once) ---
  for (int r = tid; r < 576; r += 256) {
    int tap = r >> 6, wo = r & 63;
    float dy = off[((b * 18 + 2 * tap)     * 64 + ho) * 64 + wo];
    float dx = off[((b * 18 + 2 * tap + 1) * 64 + ho) * 64 + wo];
    float py = (float)(ho + (tap / 3) - 1) + dy;
    float px = (float)(wo + (tap % 3) - 1) + dx;
    float fy = floorf(py), fx = floorf(px);
    int y0 = (int)fy, x0 = (int)fx;
    float wy = py - fy, wx = px - fx;
    float wt = (y0 >= 0 && y0 < 64) ? (1.f - wy) : 0.f;
    float wb = (y0 + 1 >= 0 && y0 + 1 < 64) ? wy : 0.f;
    int y0c = min(max(y0, 0), 63), y1c = min(max(y0 + 1, 0), 63);
    int bx; float wl, wr;
    if (x0 >= 0 && x0 <= 62)      { bx = x0; wl = 1.f - wx; wr = wx;       }
    else if (x0 == -1)            { bx = 0;  wl = wx;       wr = 0.f;      }
    else if (x0 == 63)            { bx = 62; wl = 0.f;      wr = 1.f - wx; }
    else                          { bx = 0;  wl = 0.f;      wr = 0.f;      }
    sPos[r] = make_int2(y0c * 64 + bx, y1c * 64 + bx);
    sWt[r]  = make_float4(wt * wl, wt * wr, wb * wl, wb * wr);
  }
  __syncthreads();   // the ONLY barrier

  const int w  = tid >> 6;        // wave -> wo base 16w
  const int ln = tid & 15;        // n within MFMA tile
  const int kg = (tid >> 4) & 3;  // k-group (8 channels)
  const int wo = w * 16 + ln;

  const float* xb = x + ((size_t)b * 128 + (size_t)kg * 8) * 4096;
  const unsigned short* wfb = wf + (size_t)(tid & 63) * 8;

  f32x4 acc[8] = {};

  for (int cc = 0; cc < 4; ++cc) {          // channel-chunk outer: x-plane reuse
    const float* xp0 = xb + (size_t)cc * 32 * 4096;
#pragma unroll
    for (int tap = 0; tap < 9; ++tap) {
      const int ch = cc * 9 + tap;
      const int2   a  = sPos[tap * 64 + wo];
      const float4 wv = sWt[tap * 64 + wo];

      // gather: 8 channels x (top,bottom) row pairs
      float2 T[8], Bo[8];
      const float* xp = xp0;
#pragma unroll
      for (int j = 0; j < 8; ++j) {
        __builtin_memcpy(&T[j],  xp + a.x, 8);
        __builtin_memcpy(&Bo[j], xp + a.y, 8);
        xp += 4096;
      }

      // interpolate + pack -> this lane's B-fragment
      float v[8];
#pragma unroll
      for (int j = 0; j < 8; ++j)
        v[j] = wv.x * T[j].x + wv.y * T[j].y + wv.z * Bo[j].x + wv.w * Bo[j].y;
      u32x4 pk;
      pk.x = f2bf(v[0]) | (f2bf(v[1]) << 16);
      pk.y = f2bf(v[2]) | (f2bf(v[3]) << 16);
      pk.z = f2bf(v[4]) | (f2bf(v[5]) << 16);
      pk.w = f2bf(v[6]) | (f2bf(v[7]) << 16);
      s16x8 bfrag;
      __builtin_memcpy(&bfrag, &pk, 16);

      // A-fragments (coalesced, L1-shared across the block's waves) + MFMA
      const unsigned short* wp = wfb + (size_t)(ch * 8) * 64 * 8;
#pragma unroll
      for (int mt = 0; mt < 8; ++mt) {
        s16x8 afrag = *reinterpret_cast<const s16x8*>(wp + (size_t)mt * 64 * 8);
        acc[mt] = __builtin_amdgcn_mfma_f32_16x16x32_bf16(afrag, bfrag, acc[mt], 0, 0, 0);
      }
    }
  }

  // epilogue: C/D layout col = lane&15, row = (lane>>4)*4 + reg
#pragma unroll
  for (int mt = 0; mt < 8; ++mt)
#pragma unroll
    for (int rg = 0; rg < 4; ++rg) {
      int co = mt * 16 + kg * 4 + rg;
      out[((b * 128 + co) * 64 + ho) * 64 + wo] = acc[mt][rg];
    }
}

extern "C" void kernel_launch(void* const* d_in, const int* in_sizes, int n_in,
                              void* d_out, int out_size, void* d_ws, size_t ws_size,
                              hipStream_t stream) {
  (void)in_sizes; (void)n_in; (void)out_size; (void)ws_size;
  const float* x   = (const float*)d_in[0];
  const float* off = (const float*)d_in[1];
  const float* w   = (const float*)d_in[2];
  float* out = (float*)d_out;
  unsigned short* wf = (unsigned short*)d_ws;  // 294912 bytes

  wtrans_kernel<<<72, 256, 0, stream>>>(w, wf);
  deform_kernel<<<512, 256, 0, stream>>>(x, off, wf, out);
}